// Round 13
// baseline (398.700 us; speedup 1.0000x reference)
//
#include <hip/hip_runtime.h>
#include <hip/hip_bf16.h>
#include <hip/hip_fp16.h>

// Problem constants (fixed by the reference setup)
#define N_NODES 50000
#define N_EDGES 800000
#define E_TOT   (N_EDGES + N_NODES)   // 850000 (self-loops appended)
#define IN_C    256
#define H1C     256                    // HEADS * HID_C = 4*64
#define HEADS   4
#define HID_C   64
#define OUT_C   128
#define N_GRAPHS 100
#define NEG_SLOPE 0.2f
#define EPS_F 1e-16f
#define SCAN_BLOCKS 196               // ceil(N_NODES / 256)

// prep_kernel block partition
#define PREP_CAST_BLOCKS   12500      // 3,200,000 uint2 / 256
#define PREP_W1_BLOCKS     256        // 65536 / 256
#define PREP_W2_BLOCKS     128        // 32768 / 256
#define PREP_HIST_BLOCKS   3321       // ceil(850000/256)
#define PREP_BOUNDS_BLOCKS 196
#define PREP_TOTAL (PREP_CAST_BLOCKS + PREP_W1_BLOCKS + PREP_W2_BLOCKS + PREP_HIST_BLOCKS + PREP_BOUNDS_BLOCKS)

typedef _Float16 half8_t __attribute__((ext_vector_type(8)));
typedef float f32x4 __attribute__((ext_vector_type(4)));

// ---------------------------------------------------------------------------
// Fused prep: cast_x + W1 transpose + W2 transpose + hist + bounds.
// ---------------------------------------------------------------------------
__global__ __launch_bounds__(256) void prep_kernel(const float* __restrict__ x,
                                                   _Float16* __restrict__ xh,
                                                   const float* __restrict__ W1,
                                                   _Float16* __restrict__ W1t,
                                                   const float* __restrict__ W2,
                                                   _Float16* __restrict__ W2t,
                                                   const int* __restrict__ ei,
                                                   int* __restrict__ hist,
                                                   const int* __restrict__ batch,
                                                   int* __restrict__ gstart) {
    int b = blockIdx.x;
    int tid = threadIdx.x;
    if (b < PREP_CAST_BLOCKS) {
        int idx = b * 256 + tid;                      // < 3,200,000 exactly
        float4 v = reinterpret_cast<const float4*>(x)[idx];
        union { _Float16 h[4]; uint2 u; } p;
        p.h[0] = (_Float16)v.x; p.h[1] = (_Float16)v.y;
        p.h[2] = (_Float16)v.z; p.h[3] = (_Float16)v.w;
        reinterpret_cast<uint2*>(xh)[idx] = p.u;
        return;
    }
    b -= PREP_CAST_BLOCKS;
    if (b < PREP_W1_BLOCKS) {
        int idx = b * 256 + tid;                      // < 65536 exactly
        int n = idx >> 8, k = idx & 255;
        W1t[idx] = (_Float16)W1[k * 256 + n];
        return;
    }
    b -= PREP_W1_BLOCKS;
    if (b < PREP_W2_BLOCKS) {
        int idx = b * 256 + tid;                      // < 32768 exactly
        int n = idx >> 8, k = idx & 255;
        W2t[idx] = (_Float16)W2[k * 128 + n];
        return;
    }
    b -= PREP_W2_BLOCKS;
    if (b < PREP_HIST_BLOCKS) {
        int idx = b * 256 + tid;
        if (idx < N_EDGES) {
            int d = ei[N_EDGES + idx];
            if (d >= 0 && d < N_NODES) atomicAdd(&hist[d], 1);
        } else if (idx < E_TOT) {
            atomicAdd(&hist[idx - N_EDGES], 1);       // self loop
        }
        return;
    }
    b -= PREP_HIST_BLOCKS;
    {   // bounds: batch sorted; each gstart entry written exactly once
        int idx = b * 256 + tid;
        if (idx >= N_NODES) return;
        int g = batch[idx];
        if (g < 0) g = 0; if (g >= N_GRAPHS) g = N_GRAPHS - 1;
        if (idx == 0) {
            for (int j = 0; j <= g; ++j) gstart[j] = 0;
        } else {
            int gp = batch[idx - 1];
            if (gp < 0) gp = 0; if (gp >= N_GRAPHS) gp = N_GRAPHS - 1;
            for (int j = gp + 1; j <= g; ++j) gstart[j] = idx;
        }
        if (idx == N_NODES - 1) {
            for (int j = g + 1; j <= N_GRAPHS; ++j) gstart[j] = N_NODES;
        }
    }
}

// ---------------------------------------------------------------------------
// CSR scan (3-phase multi-block) + scatter
// ---------------------------------------------------------------------------
__global__ __launch_bounds__(256) void scan_phase1(const int* __restrict__ hist,
                                                   int* __restrict__ blockSums) {
    __shared__ int lds[256];
    int idx = blockIdx.x * 256 + threadIdx.x;
    int v = (idx < N_NODES) ? hist[idx] : 0;
    lds[threadIdx.x] = v;
    __syncthreads();
#pragma unroll
    for (int off = 128; off > 0; off >>= 1) {
        if (threadIdx.x < off) lds[threadIdx.x] += lds[threadIdx.x + off];
        __syncthreads();
    }
    if (threadIdx.x == 0) blockSums[blockIdx.x] = lds[0];
}

__global__ __launch_bounds__(256) void scan_phase2(const int* __restrict__ blockSums,
                                                   int* __restrict__ blockOffsets) {
    __shared__ int lds[256];
    int t = threadIdx.x;
    int v = (t < SCAN_BLOCKS) ? blockSums[t] : 0;
    lds[t] = v;
    __syncthreads();
#pragma unroll
    for (int off = 1; off < 256; off <<= 1) {
        int u = (t >= off) ? lds[t - off] : 0;
        __syncthreads();
        lds[t] += u;
        __syncthreads();
    }
    if (t < SCAN_BLOCKS) blockOffsets[t] = lds[t] - v;   // exclusive offsets
    if (t == 255) blockOffsets[SCAN_BLOCKS] = lds[255];  // grand total
}

__global__ __launch_bounds__(256) void scan_phase3(const int* __restrict__ hist,
                                                   const int* __restrict__ blockOffsets,
                                                   int* __restrict__ row_ptr,
                                                   int* __restrict__ row_fill) {
    __shared__ int lds[256];
    int idx = blockIdx.x * 256 + threadIdx.x;
    int t = threadIdx.x;
    int v = (idx < N_NODES) ? hist[idx] : 0;
    lds[t] = v;
    __syncthreads();
#pragma unroll
    for (int off = 1; off < 256; off <<= 1) {
        int u = (t >= off) ? lds[t - off] : 0;
        __syncthreads();
        lds[t] += u;
        __syncthreads();
    }
    int excl = lds[t] - v + blockOffsets[blockIdx.x];
    if (idx < N_NODES) {
        row_ptr[idx] = excl;
        row_fill[idx] = excl;
    }
    if (idx == N_NODES - 1) row_ptr[N_NODES] = excl + v;
}

__global__ void scatter_kernel(const int* __restrict__ ei, int* __restrict__ row_fill,
                               int* __restrict__ ssrc) {
    int idx = blockIdx.x * 256 + threadIdx.x;
    if (idx < N_EDGES) {
        int s = ei[idx];
        int d = ei[N_EDGES + idx];
        if (s < 0 || s >= N_NODES || d < 0 || d >= N_NODES) return;  // defensive
        int pos = atomicAdd(&row_fill[d], 1);
        if (pos >= 0 && pos < E_TOT) ssrc[pos] = s;
    } else if (idx < E_TOT) {
        int nd = idx - N_EDGES;
        int pos = atomicAdd(&row_fill[nd], 1);
        if (pos >= 0 && pos < E_TOT) ssrc[pos] = nd;
    }
}

// ---------------------------------------------------------------------------
// MFMA fp16 GEMM with folded attention dots (modes 1/2, verified rounds 10-12)
// ---------------------------------------------------------------------------
__global__ __launch_bounds__(256) void gemm_mfma_kernel(const _Float16* __restrict__ A,
                                                        const _Float16* __restrict__ Bt,
                                                        _Float16* __restrict__ C,
                                                        int mode,
                                                        const float* __restrict__ attS,
                                                        const float* __restrict__ attD,
                                                        float* __restrict__ a_src_o,
                                                        float* __restrict__ a_dst_o,
                                                        int M, int N) {
    __shared__ _Float16 As[128][48];   // ldk=48 keeps 16B alignment everywhere
    __shared__ _Float16 Bs[128][48];
    __shared__ float lds_ps[128];
    __shared__ float lds_pd[128];
    const int tid = threadIdx.x;
    const int tileM = blockIdx.x * 128;
    const int tileN = blockIdx.y * 128;
    const int w = tid >> 6, lane = tid & 63;
    const int wm = (w >> 1) * 64, wn = (w & 1) * 64;
    const int quad = lane >> 4, mlane = lane & 15;
    const int srow = tid >> 2;           // 0..63 (rows srow and srow+64)
    const int schunk = (tid & 3) * 8;    // f16 offset within 32-k slab

    f32x4 zero = {0.f, 0.f, 0.f, 0.f};
    f32x4 acc[4][4];
#pragma unroll
    for (int i = 0; i < 4; ++i)
#pragma unroll
        for (int j = 0; j < 4; ++j) acc[i][j] = zero;

    const uint4* Av = reinterpret_cast<const uint4*>(A);   // 8 f16 per uint4; 32/row
    const uint4* Bv = reinterpret_cast<const uint4*>(Bt);
    const int r0 = tileM + srow, r1 = r0 + 64;
    const bool ok0 = r0 < M, ok1 = r1 < M;
    const int bn0 = tileN + srow, bn1 = bn0 + 64;          // N mult of 128: no guard
    const uint4 z4 = make_uint4(0, 0, 0, 0);

    for (int k0 = 0; k0 < 256; k0 += 32) {
        const int kc = (k0 >> 3) + (tid & 3);
        uint4 a0 = ok0 ? Av[(size_t)r0 * 32 + kc] : z4;
        uint4 a1 = ok1 ? Av[(size_t)r1 * 32 + kc] : z4;
        uint4 b0 = Bv[(size_t)bn0 * 32 + kc];
        uint4 b1 = Bv[(size_t)bn1 * 32 + kc];
        __syncthreads();
        *reinterpret_cast<uint4*>(&As[srow][schunk]) = a0;
        *reinterpret_cast<uint4*>(&As[srow + 64][schunk]) = a1;
        *reinterpret_cast<uint4*>(&Bs[srow][schunk]) = b0;
        *reinterpret_cast<uint4*>(&Bs[srow + 64][schunk]) = b1;
        __syncthreads();
        half8_t af[4], bf[4];
#pragma unroll
        for (int mt = 0; mt < 4; ++mt)
            af[mt] = *reinterpret_cast<const half8_t*>(&As[wm + mt * 16 + mlane][quad * 8]);
#pragma unroll
        for (int nt = 0; nt < 4; ++nt)
            bf[nt] = *reinterpret_cast<const half8_t*>(&Bs[wn + nt * 16 + mlane][quad * 8]);
#pragma unroll
        for (int mt = 0; mt < 4; ++mt)
#pragma unroll
            for (int nt = 0; nt < 4; ++nt)
                acc[mt][nt] = __builtin_amdgcn_mfma_f32_16x16x32_f16(af[mt], bf[nt], acc[mt][nt], 0, 0, 0);
    }
#pragma unroll
    for (int mt = 0; mt < 4; ++mt) {
#pragma unroll
        for (int i = 0; i < 4; ++i) {
            int row = tileM + wm + mt * 16 + quad * 4 + i;
            if (row < M) {
                _Float16* cp = C + (size_t)row * N + tileN + wn;
#pragma unroll
                for (int nt = 0; nt < 4; ++nt)
                    cp[nt * 16 + mlane] = (_Float16)acc[mt][nt][i];
            }
        }
    }
    if (mode == 1) {
        int hd = (tileN + wn) >> 6;          // this wave's head (64 cols/head)
        float as[4], ad[4];
#pragma unroll
        for (int nt = 0; nt < 4; ++nt) {
            as[nt] = attS[hd * 64 + nt * 16 + mlane];
            ad[nt] = attD[hd * 64 + nt * 16 + mlane];
        }
#pragma unroll
        for (int mt = 0; mt < 4; ++mt) {
#pragma unroll
            for (int i = 0; i < 4; ++i) {
                float ps = acc[mt][0][i] * as[0] + acc[mt][1][i] * as[1]
                         + acc[mt][2][i] * as[2] + acc[mt][3][i] * as[3];
                float pd = acc[mt][0][i] * ad[0] + acc[mt][1][i] * ad[1]
                         + acc[mt][2][i] * ad[2] + acc[mt][3][i] * ad[3];
#pragma unroll
                for (int off = 1; off < 16; off <<= 1) {
                    ps += __shfl_xor(ps, off);
                    pd += __shfl_xor(pd, off);
                }
                if (mlane == 0) {
                    int row = tileM + wm + mt * 16 + quad * 4 + i;
                    if (row < M) {
                        a_src_o[row * 4 + hd] = ps;
                        a_dst_o[row * 4 + hd] = pd;
                    }
                }
            }
        }
    } else if (mode == 2) {
        // single-head: wave covers cols wn..wn+63 of 128 -> partial dots
        float as[4], ad[4];
#pragma unroll
        for (int nt = 0; nt < 4; ++nt) {
            as[nt] = attS[wn + nt * 16 + mlane];
            ad[nt] = attD[wn + nt * 16 + mlane];
        }
        float psa[4][4], pda[4][4];
#pragma unroll
        for (int mt = 0; mt < 4; ++mt) {
#pragma unroll
            for (int i = 0; i < 4; ++i) {
                float ps = acc[mt][0][i] * as[0] + acc[mt][1][i] * as[1]
                         + acc[mt][2][i] * as[2] + acc[mt][3][i] * as[3];
                float pd = acc[mt][0][i] * ad[0] + acc[mt][1][i] * ad[1]
                         + acc[mt][2][i] * ad[2] + acc[mt][3][i] * ad[3];
#pragma unroll
                for (int off = 1; off < 16; off <<= 1) {
                    ps += __shfl_xor(ps, off);
                    pd += __shfl_xor(pd, off);
                }
                psa[mt][i] = ps; pda[mt][i] = pd;
            }
        }
        __syncthreads();
        if (wn == 0 && mlane == 0) {
#pragma unroll
            for (int mt = 0; mt < 4; ++mt)
#pragma unroll
                for (int i = 0; i < 4; ++i) {
                    int lr = wm + mt * 16 + quad * 4 + i;
                    lds_ps[lr] = psa[mt][i];
                    lds_pd[lr] = pda[mt][i];
                }
        }
        __syncthreads();
        if (wn == 64 && mlane == 0) {
#pragma unroll
            for (int mt = 0; mt < 4; ++mt)
#pragma unroll
                for (int i = 0; i < 4; ++i) {
                    int lr = wm + mt * 16 + quad * 4 + i;
                    int row = tileM + lr;
                    if (row < M) {
                        a_src_o[row] = psa[mt][i] + lds_ps[lr];
                        a_dst_o[row] = pda[mt][i] + lds_pd[lr];
                    }
                }
        }
    }
}

__device__ __forceinline__ float lrelu(float x) { return x > 0.f ? x : NEG_SLOPE * x; }

// ---------------------------------------------------------------------------
// Edge aggregation, layer 1 — single pass, SHUFFLE-DISTRIBUTED exps.
// Round-12 profile: VALU 58% with 16 lanes/head redundantly computing the
// same exp per edge. Now edges are processed in chunks of 16: lane p of each
// head group computes exp for edge base+p only; per-edge weight+index are
// broadcast in-register via __shfl (no extra memory traffic — the round-9
// mistake). Denominator = intra-group shuffle reduction at the end.
// Full chunks unroll 16 independent row-gathers (vs 4 before) for MLP.
// ---------------------------------------------------------------------------
__global__ __launch_bounds__(256) void edge1_kernel(const int* __restrict__ row_ptr,
                                                    const int* __restrict__ ssrc,
                                                    const __half* __restrict__ h1h,
                                                    const float* __restrict__ a_src,
                                                    const float* __restrict__ a_dst,
                                                    const float* __restrict__ bias,
                                                    __half* __restrict__ out) {
    int node = blockIdx.x * 4 + (threadIdx.x >> 6);
    int lane = threadIdx.x & 63;
    int hd = lane >> 4, p = lane & 15;
    int start = row_ptr[node], end = row_ptr[node + 1];
    float adh = a_dst[node * 4 + hd];

    const uint2* h1v = reinterpret_cast<const uint2*>(h1h);
    float4 accA = make_float4(0.f, 0.f, 0.f, 0.f);
    float4 accB = make_float4(0.f, 0.f, 0.f, 0.f);
    float s = 0.f;
    const int srcl = hd << 4;

    for (int base = start; base < end; base += 16) {
        int rem = end - base; if (rem > 16) rem = 16;
        float w = 0.f; int si = 0;
        if (p < rem) {
            si = ssrc[base + p];
            float r = a_src[si * 4 + hd];
            w = __expf(lrelu(r + adh));
        }
        s += w;
        if (rem == 16) {
#pragma unroll
            for (int j = 0; j < 16; j += 2) {
                float wj0 = __shfl(w, srcl + j);
                int  sj0 = __shfl(si, srcl + j);
                float wj1 = __shfl(w, srcl + j + 1);
                int  sj1 = __shfl(si, srcl + j + 1);
                uint2 q0 = h1v[(size_t)sj0 * 64 + lane];
                uint2 q1 = h1v[(size_t)sj1 * 64 + lane];
                float2 f0a = __half22float2(*reinterpret_cast<const __half2*>(&q0.x));
                float2 f0b = __half22float2(*reinterpret_cast<const __half2*>(&q0.y));
                float2 f1a = __half22float2(*reinterpret_cast<const __half2*>(&q1.x));
                float2 f1b = __half22float2(*reinterpret_cast<const __half2*>(&q1.y));
                accA.x += wj0 * f0a.x; accA.y += wj0 * f0a.y;
                accA.z += wj0 * f0b.x; accA.w += wj0 * f0b.y;
                accB.x += wj1 * f1a.x; accB.y += wj1 * f1a.y;
                accB.z += wj1 * f1b.x; accB.w += wj1 * f1b.y;
            }
        } else {
            for (int j = 0; j < rem; ++j) {
                float wj = __shfl(w, srcl + j);
                int  sj = __shfl(si, srcl + j);
                uint2 q = h1v[(size_t)sj * 64 + lane];
                float2 fa = __half22float2(*reinterpret_cast<const __half2*>(&q.x));
                float2 fb = __half22float2(*reinterpret_cast<const __half2*>(&q.y));
                accA.x += wj * fa.x; accA.y += wj * fa.y;
                accA.z += wj * fb.x; accA.w += wj * fb.y;
            }
        }
    }
    // denominator: sum w over the 16 lanes of this head group
    s += __shfl_xor(s, 1);
    s += __shfl_xor(s, 2);
    s += __shfl_xor(s, 4);
    s += __shfl_xor(s, 8);
    float inv = 1.0f / (s + EPS_F);
    float4 acc;
    acc.x = (accA.x + accB.x) * inv;
    acc.y = (accA.y + accB.y) * inv;
    acc.z = (accA.z + accB.z) * inv;
    acc.w = (accA.w + accB.w) * inv;
    float4 bv = reinterpret_cast<const float4*>(bias)[lane];
    union { __half h[4]; uint2 u; } st;
    st.h[0] = __float2half(fmaxf(acc.x + bv.x, 0.f));
    st.h[1] = __float2half(fmaxf(acc.y + bv.y, 0.f));
    st.h[2] = __float2half(fmaxf(acc.z + bv.z, 0.f));
    st.h[3] = __float2half(fmaxf(acc.w + bv.w, 0.f));
    reinterpret_cast<uint2*>(out)[(size_t)node * 64 + lane] = st.u;
}

// ---------------------------------------------------------------------------
// Edge aggregation, layer 2 — single pass, shuffle-distributed exps
// (chunk 64: lane p computes exp for edge base+p; broadcast via __shfl).
// ---------------------------------------------------------------------------
__global__ __launch_bounds__(256) void edge2_kernel(const int* __restrict__ row_ptr,
                                                    const int* __restrict__ ssrc,
                                                    const __half* __restrict__ h2h,
                                                    const float* __restrict__ a_src,
                                                    const float* __restrict__ a_dst,
                                                    const float* __restrict__ bias,
                                                    float* __restrict__ out) {
    int node = blockIdx.x * 4 + (threadIdx.x >> 6);
    int lane = threadIdx.x & 63;
    int start = row_ptr[node], end = row_ptr[node + 1];
    float ad = a_dst[node];

    const __half2* h2v = reinterpret_cast<const __half2*>(h2h);
    float2 accA = make_float2(0.f, 0.f);
    float2 accB = make_float2(0.f, 0.f);
    float s = 0.f;

    for (int base = start; base < end; base += 64) {
        int rem = end - base; if (rem > 64) rem = 64;
        float w = 0.f; int si = 0;
        if (lane < rem) {
            si = ssrc[base + lane];
            w = __expf(lrelu(a_src[si] + ad));
        }
        s += w;
        int j = 0;
        for (; j + 2 <= rem; j += 2) {
            float wj0 = __shfl(w, j);
            int  sj0 = __shfl(si, j);
            float wj1 = __shfl(w, j + 1);
            int  sj1 = __shfl(si, j + 1);
            float2 v0 = __half22float2(h2v[(size_t)sj0 * 64 + lane]);
            float2 v1 = __half22float2(h2v[(size_t)sj1 * 64 + lane]);
            accA.x += wj0 * v0.x; accA.y += wj0 * v0.y;
            accB.x += wj1 * v1.x; accB.y += wj1 * v1.y;
        }
        for (; j < rem; ++j) {
            float wj = __shfl(w, j);
            int  sj = __shfl(si, j);
            float2 v = __half22float2(h2v[(size_t)sj * 64 + lane]);
            accA.x += wj * v.x; accA.y += wj * v.y;
        }
    }
#pragma unroll
    for (int off = 1; off < 64; off <<= 1) s += __shfl_xor(s, off);
    float inv = 1.0f / (s + EPS_F);
    float2 acc;
    acc.x = (accA.x + accB.x) * inv;
    acc.y = (accA.y + accB.y) * inv;
    float2 bv = reinterpret_cast<const float2*>(bias)[lane];
    acc.x = fmaxf(acc.x + bv.x, 0.f);
    acc.y = fmaxf(acc.y + bv.y, 0.f);
    reinterpret_cast<float2*>(out)[(size_t)node * 64 + lane] = acc;
}

// ---------------------------------------------------------------------------
// Pooling with folded mean division (replaces final_kernel): batch sorted ->
// per-block running accumulator; each flush adds acc/cnt(graph).
// ---------------------------------------------------------------------------
__global__ __launch_bounds__(128) void pool_kernel(const float* __restrict__ out2,
                                                   const int* __restrict__ batch,
                                                   const int* __restrict__ gstart,
                                                   float* __restrict__ d_out) {
    int c = threadIdx.x;                 // channel 0..127
    int node0 = blockIdx.x * 128;
    int nodeEnd = node0 + 128; if (nodeEnd > N_NODES) nodeEnd = N_NODES;
    if (node0 >= N_NODES) return;
    int gprev = batch[node0];
    float acc = 0.f;
    for (int node = node0; node < nodeEnd; ++node) {
        int g = batch[node];
        if (g != gprev) {
            if (gprev >= 0 && gprev < N_GRAPHS) {
                float cnt = (float)(gstart[gprev + 1] - gstart[gprev]);
                if (cnt < 1.f) cnt = 1.f;
                atomicAdd(&d_out[gprev * 128 + c], acc / cnt);
            }
            acc = 0.f;
            gprev = g;
        }
        acc += out2[(size_t)node * 128 + c];
    }
    if (gprev >= 0 && gprev < N_GRAPHS) {
        float cnt = (float)(gstart[gprev + 1] - gstart[gprev]);
        if (cnt < 1.f) cnt = 1.f;
        atomicAdd(&d_out[gprev * 128 + c], acc / cnt);
    }
}

// ---------------------------------------------------------------------------
extern "C" void kernel_launch(void* const* d_in, const int* in_sizes, int n_in,
                              void* d_out_v, int out_size, void* d_ws, size_t ws_size,
                              hipStream_t stream) {
    const float* x      = (const float*)d_in[0];
    const float* W1     = (const float*)d_in[1];
    const float* att_s1 = (const float*)d_in[2];
    const float* att_d1 = (const float*)d_in[3];
    const float* bias1  = (const float*)d_in[4];
    const float* W2     = (const float*)d_in[5];
    const float* att_s2 = (const float*)d_in[6];
    const float* att_d2 = (const float*)d_in[7];
    const float* bias2  = (const float*)d_in[8];
    const int*   ei     = (const int*)d_in[9];
    const int*   batch  = (const int*)d_in[10];
    float* d_out = (float*)d_out_v;

    // Workspace layout (float units):
    //  [0, 6.4M)        xh fp16 [N,256]      ... later reused as h2h fp16 [N,128]
    //  [6.4M, 12.8M)    h1h fp16 [N,256]     ... later reused as out2 fp32 [N,128]
    //  [12.8M, 19.2M)   out1h fp16 [N,256]
    //  [19.2M, ...)     attention scalars + CSR ints + W transposes
    float* ws = (float*)d_ws;
    _Float16* xh    = (_Float16*)ws;
    _Float16* h1h   = (_Float16*)(ws + 6400000);
    _Float16* out1h = (_Float16*)(ws + 12800000);
    _Float16* h2h   = (_Float16*)ws;            // xh dead after GEMM1
    float*    out2  = ws + 6400000;             // h1h dead after edge1
    float* a_src1 = ws + 19200000;              // N*4
    float* a_dst1 = a_src1 + 200000;            // N*4
    float* a_src2 = a_dst1 + 200000;            // N
    float* a_dst2 = a_src2 + 50000;             // N
    int* hist     = (int*)(a_dst2 + 50000);     // N
    int* row_ptr  = hist + 50000;               // N+1 (padded to 50016)
    int* row_fill = row_ptr + 50016;            // N (padded to 50016)
    int* ssrc     = row_fill + 50016;           // E_TOT
    int* gstart   = ssrc + E_TOT;               // N_GRAPHS+1 (pad 128)
    int* blockSums    = gstart + 128;           // SCAN_BLOCKS
    int* blockOffsets = blockSums + SCAN_BLOCKS;     // SCAN_BLOCKS+1 (pad 256)
    _Float16* W1t = (_Float16*)(blockOffsets + 256); // 65536 halfs [256][256]
    _Float16* W2t = W1t + 65536;                     // 32768 halfs [128][256]

    // Zero what must be zero
    hipMemsetAsync(hist, 0, N_NODES * sizeof(int), stream);
    hipMemsetAsync(d_out, 0, N_GRAPHS * 128 * sizeof(float), stream);

    // Fused prep: cast x, transpose W1/W2, histogram, graph bounds
    prep_kernel<<<PREP_TOTAL, 256, 0, stream>>>(x, xh, W1, W1t, W2, W2t,
                                                ei, hist, batch, gstart);

    // CSR scan + scatter
    scan_phase1<<<SCAN_BLOCKS, 256, 0, stream>>>(hist, blockSums);
    scan_phase2<<<1, 256, 0, stream>>>(blockSums, blockOffsets);
    scan_phase3<<<SCAN_BLOCKS, 256, 0, stream>>>(hist, blockOffsets, row_ptr, row_fill);
    scatter_kernel<<<(E_TOT + 255) / 256, 256, 0, stream>>>(ei, row_fill, ssrc);

    // Layer 1: h1 = x @ W1 (MFMA fp16, att1 folded into epilogue, mode 1)
    {
        dim3 g((N_NODES + 127) / 128, H1C / 128);
        gemm_mfma_kernel<<<g, 256, 0, stream>>>(xh, W1t, h1h, 1,
                                                att_s1, att_d1, a_src1, a_dst1,
                                                N_NODES, H1C);
    }
    edge1_kernel<<<N_NODES / 4, 256, 0, stream>>>(row_ptr, ssrc, (const __half*)h1h,
                                                  a_src1, a_dst1, bias1, (__half*)out1h);

    // Layer 2: h2 = out1 @ W2 (MFMA fp16, att2 folded via LDS combine, mode 2)
    {
        dim3 g((N_NODES + 127) / 128, OUT_C / 128);
        gemm_mfma_kernel<<<g, 256, 0, stream>>>(out1h, W2t, h2h, 2,
                                                att_s2, att_d2, a_src2, a_dst2,
                                                N_NODES, OUT_C);
    }
    edge2_kernel<<<N_NODES / 4, 256, 0, stream>>>(row_ptr, ssrc, (const __half*)h2h,
                                                  a_src2, a_dst2, bias2, out2);

    // Pooling (mean division folded into the atomic flush)
    pool_kernel<<<(N_NODES + 127) / 128, 128, 0, stream>>>(out2, batch, gstart, d_out);
}

// Round 14
// 387.783 us; speedup vs baseline: 1.0282x; 1.0282x over previous
//
#include <hip/hip_runtime.h>
#include <hip/hip_bf16.h>
#include <hip/hip_fp16.h>

// Problem constants (fixed by the reference setup)
#define N_NODES 50000
#define N_EDGES 800000
#define E_TOT   (N_EDGES + N_NODES)   // 850000 (self-loops appended)
#define IN_C    256
#define H1C     256                    // HEADS * HID_C = 4*64
#define HEADS   4
#define HID_C   64
#define OUT_C   128
#define N_GRAPHS 100
#define NEG_SLOPE 0.2f
#define EPS_F 1e-16f
#define SCAN_BLOCKS 196               // ceil(N_NODES / 256)

// prep_kernel block partition
#define PREP_CAST_BLOCKS   12500      // 3,200,000 uint2 / 256
#define PREP_W1_BLOCKS     256        // 65536 / 256
#define PREP_W2_BLOCKS     128        // 32768 / 256
#define PREP_HIST_BLOCKS   3321       // ceil(850000/256)
#define PREP_BOUNDS_BLOCKS 196
#define PREP_TOTAL (PREP_CAST_BLOCKS + PREP_W1_BLOCKS + PREP_W2_BLOCKS + PREP_HIST_BLOCKS + PREP_BOUNDS_BLOCKS)

typedef _Float16 half8_t __attribute__((ext_vector_type(8)));
typedef float f32x4 __attribute__((ext_vector_type(4)));

// ---------------------------------------------------------------------------
// Fused prep: cast_x + W1 transpose + W2 transpose + hist + bounds.
// ---------------------------------------------------------------------------
__global__ __launch_bounds__(256) void prep_kernel(const float* __restrict__ x,
                                                   _Float16* __restrict__ xh,
                                                   const float* __restrict__ W1,
                                                   _Float16* __restrict__ W1t,
                                                   const float* __restrict__ W2,
                                                   _Float16* __restrict__ W2t,
                                                   const int* __restrict__ ei,
                                                   int* __restrict__ hist,
                                                   const int* __restrict__ batch,
                                                   int* __restrict__ gstart) {
    int b = blockIdx.x;
    int tid = threadIdx.x;
    if (b < PREP_CAST_BLOCKS) {
        int idx = b * 256 + tid;                      // < 3,200,000 exactly
        float4 v = reinterpret_cast<const float4*>(x)[idx];
        union { _Float16 h[4]; uint2 u; } p;
        p.h[0] = (_Float16)v.x; p.h[1] = (_Float16)v.y;
        p.h[2] = (_Float16)v.z; p.h[3] = (_Float16)v.w;
        reinterpret_cast<uint2*>(xh)[idx] = p.u;
        return;
    }
    b -= PREP_CAST_BLOCKS;
    if (b < PREP_W1_BLOCKS) {
        int idx = b * 256 + tid;                      // < 65536 exactly
        int n = idx >> 8, k = idx & 255;
        W1t[idx] = (_Float16)W1[k * 256 + n];
        return;
    }
    b -= PREP_W1_BLOCKS;
    if (b < PREP_W2_BLOCKS) {
        int idx = b * 256 + tid;                      // < 32768 exactly
        int n = idx >> 8, k = idx & 255;
        W2t[idx] = (_Float16)W2[k * 128 + n];
        return;
    }
    b -= PREP_W2_BLOCKS;
    if (b < PREP_HIST_BLOCKS) {
        int idx = b * 256 + tid;
        if (idx < N_EDGES) {
            int d = ei[N_EDGES + idx];
            if (d >= 0 && d < N_NODES) atomicAdd(&hist[d], 1);
        } else if (idx < E_TOT) {
            atomicAdd(&hist[idx - N_EDGES], 1);       // self loop
        }
        return;
    }
    b -= PREP_HIST_BLOCKS;
    {   // bounds: batch sorted; each gstart entry written exactly once
        int idx = b * 256 + tid;
        if (idx >= N_NODES) return;
        int g = batch[idx];
        if (g < 0) g = 0; if (g >= N_GRAPHS) g = N_GRAPHS - 1;
        if (idx == 0) {
            for (int j = 0; j <= g; ++j) gstart[j] = 0;
        } else {
            int gp = batch[idx - 1];
            if (gp < 0) gp = 0; if (gp >= N_GRAPHS) gp = N_GRAPHS - 1;
            for (int j = gp + 1; j <= g; ++j) gstart[j] = idx;
        }
        if (idx == N_NODES - 1) {
            for (int j = g + 1; j <= N_GRAPHS; ++j) gstart[j] = N_NODES;
        }
    }
}

// ---------------------------------------------------------------------------
// CSR scan (3-phase multi-block) + scatter
// ---------------------------------------------------------------------------
__global__ __launch_bounds__(256) void scan_phase1(const int* __restrict__ hist,
                                                   int* __restrict__ blockSums) {
    __shared__ int lds[256];
    int idx = blockIdx.x * 256 + threadIdx.x;
    int v = (idx < N_NODES) ? hist[idx] : 0;
    lds[threadIdx.x] = v;
    __syncthreads();
#pragma unroll
    for (int off = 128; off > 0; off >>= 1) {
        if (threadIdx.x < off) lds[threadIdx.x] += lds[threadIdx.x + off];
        __syncthreads();
    }
    if (threadIdx.x == 0) blockSums[blockIdx.x] = lds[0];
}

__global__ __launch_bounds__(256) void scan_phase2(const int* __restrict__ blockSums,
                                                   int* __restrict__ blockOffsets) {
    __shared__ int lds[256];
    int t = threadIdx.x;
    int v = (t < SCAN_BLOCKS) ? blockSums[t] : 0;
    lds[t] = v;
    __syncthreads();
#pragma unroll
    for (int off = 1; off < 256; off <<= 1) {
        int u = (t >= off) ? lds[t - off] : 0;
        __syncthreads();
        lds[t] += u;
        __syncthreads();
    }
    if (t < SCAN_BLOCKS) blockOffsets[t] = lds[t] - v;   // exclusive offsets
    if (t == 255) blockOffsets[SCAN_BLOCKS] = lds[255];  // grand total
}

__global__ __launch_bounds__(256) void scan_phase3(const int* __restrict__ hist,
                                                   const int* __restrict__ blockOffsets,
                                                   int* __restrict__ row_ptr,
                                                   int* __restrict__ row_fill) {
    __shared__ int lds[256];
    int idx = blockIdx.x * 256 + threadIdx.x;
    int t = threadIdx.x;
    int v = (idx < N_NODES) ? hist[idx] : 0;
    lds[t] = v;
    __syncthreads();
#pragma unroll
    for (int off = 1; off < 256; off <<= 1) {
        int u = (t >= off) ? lds[t - off] : 0;
        __syncthreads();
        lds[t] += u;
        __syncthreads();
    }
    int excl = lds[t] - v + blockOffsets[blockIdx.x];
    if (idx < N_NODES) {
        row_ptr[idx] = excl;
        row_fill[idx] = excl;
    }
    if (idx == N_NODES - 1) row_ptr[N_NODES] = excl + v;
}

__global__ void scatter_kernel(const int* __restrict__ ei, int* __restrict__ row_fill,
                               int* __restrict__ ssrc) {
    int idx = blockIdx.x * 256 + threadIdx.x;
    if (idx < N_EDGES) {
        int s = ei[idx];
        int d = ei[N_EDGES + idx];
        if (s < 0 || s >= N_NODES || d < 0 || d >= N_NODES) return;  // defensive
        int pos = atomicAdd(&row_fill[d], 1);
        if (pos >= 0 && pos < E_TOT) ssrc[pos] = s;
    } else if (idx < E_TOT) {
        int nd = idx - N_EDGES;
        int pos = atomicAdd(&row_fill[nd], 1);
        if (pos >= 0 && pos < E_TOT) ssrc[pos] = nd;
    }
}

// ---------------------------------------------------------------------------
// MFMA fp16 GEMM with folded attention dots (modes 1/2, verified rounds 10-12)
// ---------------------------------------------------------------------------
__global__ __launch_bounds__(256) void gemm_mfma_kernel(const _Float16* __restrict__ A,
                                                        const _Float16* __restrict__ Bt,
                                                        _Float16* __restrict__ C,
                                                        int mode,
                                                        const float* __restrict__ attS,
                                                        const float* __restrict__ attD,
                                                        float* __restrict__ a_src_o,
                                                        float* __restrict__ a_dst_o,
                                                        int M, int N) {
    __shared__ _Float16 As[128][48];   // ldk=48 keeps 16B alignment everywhere
    __shared__ _Float16 Bs[128][48];
    __shared__ float lds_ps[128];
    __shared__ float lds_pd[128];
    const int tid = threadIdx.x;
    const int tileM = blockIdx.x * 128;
    const int tileN = blockIdx.y * 128;
    const int w = tid >> 6, lane = tid & 63;
    const int wm = (w >> 1) * 64, wn = (w & 1) * 64;
    const int quad = lane >> 4, mlane = lane & 15;
    const int srow = tid >> 2;           // 0..63 (rows srow and srow+64)
    const int schunk = (tid & 3) * 8;    // f16 offset within 32-k slab

    f32x4 zero = {0.f, 0.f, 0.f, 0.f};
    f32x4 acc[4][4];
#pragma unroll
    for (int i = 0; i < 4; ++i)
#pragma unroll
        for (int j = 0; j < 4; ++j) acc[i][j] = zero;

    const uint4* Av = reinterpret_cast<const uint4*>(A);   // 8 f16 per uint4; 32/row
    const uint4* Bv = reinterpret_cast<const uint4*>(Bt);
    const int r0 = tileM + srow, r1 = r0 + 64;
    const bool ok0 = r0 < M, ok1 = r1 < M;
    const int bn0 = tileN + srow, bn1 = bn0 + 64;          // N mult of 128: no guard
    const uint4 z4 = make_uint4(0, 0, 0, 0);

    for (int k0 = 0; k0 < 256; k0 += 32) {
        const int kc = (k0 >> 3) + (tid & 3);
        uint4 a0 = ok0 ? Av[(size_t)r0 * 32 + kc] : z4;
        uint4 a1 = ok1 ? Av[(size_t)r1 * 32 + kc] : z4;
        uint4 b0 = Bv[(size_t)bn0 * 32 + kc];
        uint4 b1 = Bv[(size_t)bn1 * 32 + kc];
        __syncthreads();
        *reinterpret_cast<uint4*>(&As[srow][schunk]) = a0;
        *reinterpret_cast<uint4*>(&As[srow + 64][schunk]) = a1;
        *reinterpret_cast<uint4*>(&Bs[srow][schunk]) = b0;
        *reinterpret_cast<uint4*>(&Bs[srow + 64][schunk]) = b1;
        __syncthreads();
        half8_t af[4], bf[4];
#pragma unroll
        for (int mt = 0; mt < 4; ++mt)
            af[mt] = *reinterpret_cast<const half8_t*>(&As[wm + mt * 16 + mlane][quad * 8]);
#pragma unroll
        for (int nt = 0; nt < 4; ++nt)
            bf[nt] = *reinterpret_cast<const half8_t*>(&Bs[wn + nt * 16 + mlane][quad * 8]);
#pragma unroll
        for (int mt = 0; mt < 4; ++mt)
#pragma unroll
            for (int nt = 0; nt < 4; ++nt)
                acc[mt][nt] = __builtin_amdgcn_mfma_f32_16x16x32_f16(af[mt], bf[nt], acc[mt][nt], 0, 0, 0);
    }
#pragma unroll
    for (int mt = 0; mt < 4; ++mt) {
#pragma unroll
        for (int i = 0; i < 4; ++i) {
            int row = tileM + wm + mt * 16 + quad * 4 + i;
            if (row < M) {
                _Float16* cp = C + (size_t)row * N + tileN + wn;
#pragma unroll
                for (int nt = 0; nt < 4; ++nt)
                    cp[nt * 16 + mlane] = (_Float16)acc[mt][nt][i];
            }
        }
    }
    if (mode == 1) {
        int hd = (tileN + wn) >> 6;          // this wave's head (64 cols/head)
        float as[4], ad[4];
#pragma unroll
        for (int nt = 0; nt < 4; ++nt) {
            as[nt] = attS[hd * 64 + nt * 16 + mlane];
            ad[nt] = attD[hd * 64 + nt * 16 + mlane];
        }
#pragma unroll
        for (int mt = 0; mt < 4; ++mt) {
#pragma unroll
            for (int i = 0; i < 4; ++i) {
                float ps = acc[mt][0][i] * as[0] + acc[mt][1][i] * as[1]
                         + acc[mt][2][i] * as[2] + acc[mt][3][i] * as[3];
                float pd = acc[mt][0][i] * ad[0] + acc[mt][1][i] * ad[1]
                         + acc[mt][2][i] * ad[2] + acc[mt][3][i] * ad[3];
#pragma unroll
                for (int off = 1; off < 16; off <<= 1) {
                    ps += __shfl_xor(ps, off);
                    pd += __shfl_xor(pd, off);
                }
                if (mlane == 0) {
                    int row = tileM + wm + mt * 16 + quad * 4 + i;
                    if (row < M) {
                        a_src_o[row * 4 + hd] = ps;
                        a_dst_o[row * 4 + hd] = pd;
                    }
                }
            }
        }
    } else if (mode == 2) {
        // single-head: wave covers cols wn..wn+63 of 128 -> partial dots
        float as[4], ad[4];
#pragma unroll
        for (int nt = 0; nt < 4; ++nt) {
            as[nt] = attS[wn + nt * 16 + mlane];
            ad[nt] = attD[wn + nt * 16 + mlane];
        }
        float psa[4][4], pda[4][4];
#pragma unroll
        for (int mt = 0; mt < 4; ++mt) {
#pragma unroll
            for (int i = 0; i < 4; ++i) {
                float ps = acc[mt][0][i] * as[0] + acc[mt][1][i] * as[1]
                         + acc[mt][2][i] * as[2] + acc[mt][3][i] * as[3];
                float pd = acc[mt][0][i] * ad[0] + acc[mt][1][i] * ad[1]
                         + acc[mt][2][i] * ad[2] + acc[mt][3][i] * ad[3];
#pragma unroll
                for (int off = 1; off < 16; off <<= 1) {
                    ps += __shfl_xor(ps, off);
                    pd += __shfl_xor(pd, off);
                }
                psa[mt][i] = ps; pda[mt][i] = pd;
            }
        }
        __syncthreads();
        if (wn == 0 && mlane == 0) {
#pragma unroll
            for (int mt = 0; mt < 4; ++mt)
#pragma unroll
                for (int i = 0; i < 4; ++i) {
                    int lr = wm + mt * 16 + quad * 4 + i;
                    lds_ps[lr] = psa[mt][i];
                    lds_pd[lr] = pda[mt][i];
                }
        }
        __syncthreads();
        if (wn == 64 && mlane == 0) {
#pragma unroll
            for (int mt = 0; mt < 4; ++mt)
#pragma unroll
                for (int i = 0; i < 4; ++i) {
                    int lr = wm + mt * 16 + quad * 4 + i;
                    int row = tileM + lr;
                    if (row < M) {
                        a_src_o[row] = psa[mt][i] + lds_ps[lr];
                        a_dst_o[row] = pda[mt][i] + lds_pd[lr];
                    }
                }
        }
    }
}

__device__ __forceinline__ float lrelu(float x) { return x > 0.f ? x : NEG_SLOPE * x; }

// ---------------------------------------------------------------------------
// Edge aggregation, layer 1 — round-12 form (empirical optimum: redundant
// exps co-schedule under gather latency; R9 memory-route and R13 shuffle-
// route both regressed by hurting occupancy/issue-rate). Single pass,
// deferred normalization, 4-way unrolled, 28 VGPR, ~68% occupancy.
// ---------------------------------------------------------------------------
__global__ __launch_bounds__(256) void edge1_kernel(const int* __restrict__ row_ptr,
                                                    const int* __restrict__ ssrc,
                                                    const __half* __restrict__ h1h,
                                                    const float* __restrict__ a_src,
                                                    const float* __restrict__ a_dst,
                                                    const float* __restrict__ bias,
                                                    __half* __restrict__ out) {
    int node = blockIdx.x * 4 + (threadIdx.x >> 6);
    int lane = threadIdx.x & 63;
    int start = row_ptr[node], end = row_ptr[node + 1];
    int hd = lane >> 4;
    float adh = a_dst[node * 4 + hd];

    const uint2* h1v = reinterpret_cast<const uint2*>(h1h);
    float4 acc0 = make_float4(0.f, 0.f, 0.f, 0.f);
    float4 acc1 = make_float4(0.f, 0.f, 0.f, 0.f);
    float4 acc2 = make_float4(0.f, 0.f, 0.f, 0.f);
    float4 acc3 = make_float4(0.f, 0.f, 0.f, 0.f);
    float s = 0.f;
    int e = start;
    for (; e + 4 <= end; e += 4) {
        int si0 = ssrc[e + 0];
        int si1 = ssrc[e + 1];
        int si2 = ssrc[e + 2];
        int si3 = ssrc[e + 3];
        float r0 = a_src[si0 * 4 + hd];
        float r1 = a_src[si1 * 4 + hd];
        float r2 = a_src[si2 * 4 + hd];
        float r3 = a_src[si3 * 4 + hd];
        uint2 q0 = h1v[(size_t)si0 * 64 + lane];
        uint2 q1 = h1v[(size_t)si1 * 64 + lane];
        uint2 q2 = h1v[(size_t)si2 * 64 + lane];
        uint2 q3 = h1v[(size_t)si3 * 64 + lane];
        float w0 = __expf(lrelu(r0 + adh));
        float w1 = __expf(lrelu(r1 + adh));
        float w2 = __expf(lrelu(r2 + adh));
        float w3 = __expf(lrelu(r3 + adh));
        s += (w0 + w1) + (w2 + w3);
        float2 f0a = __half22float2(*reinterpret_cast<const __half2*>(&q0.x));
        float2 f0b = __half22float2(*reinterpret_cast<const __half2*>(&q0.y));
        float2 f1a = __half22float2(*reinterpret_cast<const __half2*>(&q1.x));
        float2 f1b = __half22float2(*reinterpret_cast<const __half2*>(&q1.y));
        float2 f2a = __half22float2(*reinterpret_cast<const __half2*>(&q2.x));
        float2 f2b = __half22float2(*reinterpret_cast<const __half2*>(&q2.y));
        float2 f3a = __half22float2(*reinterpret_cast<const __half2*>(&q3.x));
        float2 f3b = __half22float2(*reinterpret_cast<const __half2*>(&q3.y));
        acc0.x += w0 * f0a.x; acc0.y += w0 * f0a.y; acc0.z += w0 * f0b.x; acc0.w += w0 * f0b.y;
        acc1.x += w1 * f1a.x; acc1.y += w1 * f1a.y; acc1.z += w1 * f1b.x; acc1.w += w1 * f1b.y;
        acc2.x += w2 * f2a.x; acc2.y += w2 * f2a.y; acc2.z += w2 * f2b.x; acc2.w += w2 * f2b.y;
        acc3.x += w3 * f3a.x; acc3.y += w3 * f3a.y; acc3.z += w3 * f3b.x; acc3.w += w3 * f3b.y;
    }
    for (; e < end; ++e) {
        int si = ssrc[e];
        float w = __expf(lrelu(a_src[si * 4 + hd] + adh));
        s += w;
        uint2 q = h1v[(size_t)si * 64 + lane];
        float2 fa = __half22float2(*reinterpret_cast<const __half2*>(&q.x));
        float2 fb = __half22float2(*reinterpret_cast<const __half2*>(&q.y));
        acc0.x += w * fa.x; acc0.y += w * fa.y; acc0.z += w * fb.x; acc0.w += w * fb.y;
    }
    float inv = 1.0f / (s + EPS_F);
    float4 acc;
    acc.x = ((acc0.x + acc1.x) + (acc2.x + acc3.x)) * inv;
    acc.y = ((acc0.y + acc1.y) + (acc2.y + acc3.y)) * inv;
    acc.z = ((acc0.z + acc1.z) + (acc2.z + acc3.z)) * inv;
    acc.w = ((acc0.w + acc1.w) + (acc2.w + acc3.w)) * inv;
    float4 bv = reinterpret_cast<const float4*>(bias)[lane];
    union { __half h[4]; uint2 u; } st;
    st.h[0] = __float2half(fmaxf(acc.x + bv.x, 0.f));
    st.h[1] = __float2half(fmaxf(acc.y + bv.y, 0.f));
    st.h[2] = __float2half(fmaxf(acc.z + bv.z, 0.f));
    st.h[3] = __float2half(fmaxf(acc.w + bv.w, 0.f));
    reinterpret_cast<uint2*>(out)[(size_t)node * 64 + lane] = st.u;
}

// ---------------------------------------------------------------------------
// Edge aggregation, layer 2 — round-12 form (single pass, deferred norm).
// ---------------------------------------------------------------------------
__global__ __launch_bounds__(256) void edge2_kernel(const int* __restrict__ row_ptr,
                                                    const int* __restrict__ ssrc,
                                                    const __half* __restrict__ h2h,
                                                    const float* __restrict__ a_src,
                                                    const float* __restrict__ a_dst,
                                                    const float* __restrict__ bias,
                                                    float* __restrict__ out) {
    int node = blockIdx.x * 4 + (threadIdx.x >> 6);
    int lane = threadIdx.x & 63;
    int start = row_ptr[node], end = row_ptr[node + 1];
    float ad = a_dst[node];

    const __half2* h2v = reinterpret_cast<const __half2*>(h2h);
    float2 acc0 = make_float2(0.f, 0.f);
    float2 acc1 = make_float2(0.f, 0.f);
    float2 acc2 = make_float2(0.f, 0.f);
    float2 acc3 = make_float2(0.f, 0.f);
    float s = 0.f;
    int e = start;
    for (; e + 4 <= end; e += 4) {
        int si0 = ssrc[e + 0];
        int si1 = ssrc[e + 1];
        int si2 = ssrc[e + 2];
        int si3 = ssrc[e + 3];
        float r0 = a_src[si0];
        float r1 = a_src[si1];
        float r2 = a_src[si2];
        float r3 = a_src[si3];
        __half2 q0 = h2v[(size_t)si0 * 64 + lane];
        __half2 q1 = h2v[(size_t)si1 * 64 + lane];
        __half2 q2 = h2v[(size_t)si2 * 64 + lane];
        __half2 q3 = h2v[(size_t)si3 * 64 + lane];
        float w0 = __expf(lrelu(r0 + ad));
        float w1 = __expf(lrelu(r1 + ad));
        float w2 = __expf(lrelu(r2 + ad));
        float w3 = __expf(lrelu(r3 + ad));
        s += (w0 + w1) + (w2 + w3);
        float2 v0 = __half22float2(q0);
        float2 v1 = __half22float2(q1);
        float2 v2 = __half22float2(q2);
        float2 v3 = __half22float2(q3);
        acc0.x += w0 * v0.x; acc0.y += w0 * v0.y;
        acc1.x += w1 * v1.x; acc1.y += w1 * v1.y;
        acc2.x += w2 * v2.x; acc2.y += w2 * v2.y;
        acc3.x += w3 * v3.x; acc3.y += w3 * v3.y;
    }
    for (; e < end; ++e) {
        int si = ssrc[e];
        float w = __expf(lrelu(a_src[si] + ad));
        s += w;
        float2 hv = __half22float2(h2v[(size_t)si * 64 + lane]);
        acc0.x += w * hv.x; acc0.y += w * hv.y;
    }
    float inv = 1.0f / (s + EPS_F);
    float2 acc;
    acc.x = ((acc0.x + acc1.x) + (acc2.x + acc3.x)) * inv;
    acc.y = ((acc0.y + acc1.y) + (acc2.y + acc3.y)) * inv;
    float2 bv = reinterpret_cast<const float2*>(bias)[lane];
    acc.x = fmaxf(acc.x + bv.x, 0.f);
    acc.y = fmaxf(acc.y + bv.y, 0.f);
    reinterpret_cast<float2*>(out)[(size_t)node * 64 + lane] = acc;
}

// ---------------------------------------------------------------------------
// Pooling with folded mean division (final_kernel removed — worth ~7 us):
// batch sorted -> per-block running accumulator; flush adds acc/cnt(graph).
// ---------------------------------------------------------------------------
__global__ __launch_bounds__(128) void pool_kernel(const float* __restrict__ out2,
                                                   const int* __restrict__ batch,
                                                   const int* __restrict__ gstart,
                                                   float* __restrict__ d_out) {
    int c = threadIdx.x;                 // channel 0..127
    int node0 = blockIdx.x * 128;
    int nodeEnd = node0 + 128; if (nodeEnd > N_NODES) nodeEnd = N_NODES;
    if (node0 >= N_NODES) return;
    int gprev = batch[node0];
    float acc = 0.f;
    for (int node = node0; node < nodeEnd; ++node) {
        int g = batch[node];
        if (g != gprev) {
            if (gprev >= 0 && gprev < N_GRAPHS) {
                float cnt = (float)(gstart[gprev + 1] - gstart[gprev]);
                if (cnt < 1.f) cnt = 1.f;
                atomicAdd(&d_out[gprev * 128 + c], acc / cnt);
            }
            acc = 0.f;
            gprev = g;
        }
        acc += out2[(size_t)node * 128 + c];
    }
    if (gprev >= 0 && gprev < N_GRAPHS) {
        float cnt = (float)(gstart[gprev + 1] - gstart[gprev]);
        if (cnt < 1.f) cnt = 1.f;
        atomicAdd(&d_out[gprev * 128 + c], acc / cnt);
    }
}

// ---------------------------------------------------------------------------
extern "C" void kernel_launch(void* const* d_in, const int* in_sizes, int n_in,
                              void* d_out_v, int out_size, void* d_ws, size_t ws_size,
                              hipStream_t stream) {
    const float* x      = (const float*)d_in[0];
    const float* W1     = (const float*)d_in[1];
    const float* att_s1 = (const float*)d_in[2];
    const float* att_d1 = (const float*)d_in[3];
    const float* bias1  = (const float*)d_in[4];
    const float* W2     = (const float*)d_in[5];
    const float* att_s2 = (const float*)d_in[6];
    const float* att_d2 = (const float*)d_in[7];
    const float* bias2  = (const float*)d_in[8];
    const int*   ei     = (const int*)d_in[9];
    const int*   batch  = (const int*)d_in[10];
    float* d_out = (float*)d_out_v;

    // Workspace layout (float units):
    //  [0, 6.4M)        xh fp16 [N,256]      ... later reused as h2h fp16 [N,128]
    //  [6.4M, 12.8M)    h1h fp16 [N,256]     ... later reused as out2 fp32 [N,128]
    //  [12.8M, 19.2M)   out1h fp16 [N,256]
    //  [19.2M, ...)     attention scalars + CSR ints + W transposes
    float* ws = (float*)d_ws;
    _Float16* xh    = (_Float16*)ws;
    _Float16* h1h   = (_Float16*)(ws + 6400000);
    _Float16* out1h = (_Float16*)(ws + 12800000);
    _Float16* h2h   = (_Float16*)ws;            // xh dead after GEMM1
    float*    out2  = ws + 6400000;             // h1h dead after edge1
    float* a_src1 = ws + 19200000;              // N*4
    float* a_dst1 = a_src1 + 200000;            // N*4
    float* a_src2 = a_dst1 + 200000;            // N
    float* a_dst2 = a_src2 + 50000;             // N
    int* hist     = (int*)(a_dst2 + 50000);     // N
    int* row_ptr  = hist + 50000;               // N+1 (padded to 50016)
    int* row_fill = row_ptr + 50016;            // N (padded to 50016)
    int* ssrc     = row_fill + 50016;           // E_TOT
    int* gstart   = ssrc + E_TOT;               // N_GRAPHS+1 (pad 128)
    int* blockSums    = gstart + 128;           // SCAN_BLOCKS
    int* blockOffsets = blockSums + SCAN_BLOCKS;     // SCAN_BLOCKS+1 (pad 256)
    _Float16* W1t = (_Float16*)(blockOffsets + 256); // 65536 halfs [256][256]
    _Float16* W2t = W1t + 65536;                     // 32768 halfs [128][256]

    // Zero what must be zero
    hipMemsetAsync(hist, 0, N_NODES * sizeof(int), stream);
    hipMemsetAsync(d_out, 0, N_GRAPHS * 128 * sizeof(float), stream);

    // Fused prep: cast x, transpose W1/W2, histogram, graph bounds
    prep_kernel<<<PREP_TOTAL, 256, 0, stream>>>(x, xh, W1, W1t, W2, W2t,
                                                ei, hist, batch, gstart);

    // CSR scan + scatter
    scan_phase1<<<SCAN_BLOCKS, 256, 0, stream>>>(hist, blockSums);
    scan_phase2<<<1, 256, 0, stream>>>(blockSums, blockOffsets);
    scan_phase3<<<SCAN_BLOCKS, 256, 0, stream>>>(hist, blockOffsets, row_ptr, row_fill);
    scatter_kernel<<<(E_TOT + 255) / 256, 256, 0, stream>>>(ei, row_fill, ssrc);

    // Layer 1: h1 = x @ W1 (MFMA fp16, att1 folded into epilogue, mode 1)
    {
        dim3 g((N_NODES + 127) / 128, H1C / 128);
        gemm_mfma_kernel<<<g, 256, 0, stream>>>(xh, W1t, h1h, 1,
                                                att_s1, att_d1, a_src1, a_dst1,
                                                N_NODES, H1C);
    }
    edge1_kernel<<<N_NODES / 4, 256, 0, stream>>>(row_ptr, ssrc, (const __half*)h1h,
                                                  a_src1, a_dst1, bias1, (__half*)out1h);

    // Layer 2: h2 = out1 @ W2 (MFMA fp16, att2 folded via LDS combine, mode 2)
    {
        dim3 g((N_NODES + 127) / 128, OUT_C / 128);
        gemm_mfma_kernel<<<g, 256, 0, stream>>>(out1h, W2t, h2h, 2,
                                                att_s2, att_d2, a_src2, a_dst2,
                                                N_NODES, OUT_C);
    }
    edge2_kernel<<<N_NODES / 4, 256, 0, stream>>>(row_ptr, ssrc, (const __half*)h2h,
                                                  a_src2, a_dst2, bias2, out2);

    // Pooling (mean division folded into the atomic flush)
    pool_kernel<<<(N_NODES + 127) / 128, 128, 0, stream>>>(out2, batch, gstart, d_out);
}